// Round 18
// baseline (10997.598 us; speedup 1.0000x reference)
//
#include <hip/hip_runtime.h>
#include <stdint.h>

#define T_ 1024

typedef float  floatx4 __attribute__((ext_vector_type(4)));
typedef short  shortx8 __attribute__((ext_vector_type(8)));
typedef unsigned long long u64;

union U16 { u64 q[2]; unsigned d[4]; shortx8 v; };

__device__ __forceinline__ unsigned short f2bf(float f) {
  union { float f; unsigned u; } v; v.f = f;
  return (unsigned short)((v.u + 0x7FFFu + ((v.u >> 16) & 1u)) >> 16);
}
__device__ __forceinline__ unsigned pkbf(float lo, float hi) {
  unsigned r;
  asm("v_cvt_pk_bf16_f32 %0, %1, %2" : "=v"(r) : "v"(lo), "v"(hi));
  return r;
}
__device__ __forceinline__ u64 lda(const u64* p) {
  return __hip_atomic_load(p, __ATOMIC_RELAXED, __HIP_MEMORY_SCOPE_AGENT);
}
__device__ __forceinline__ void sta(u64* p, u64 v) {
  __hip_atomic_store(p, v, __ATOMIC_RELAXED, __HIP_MEMORY_SCOPE_AGENT);
}

// ---- prep: zero f0 flags (512 KB) + tagged h1ring (256 KB) ----
__global__ void prep_kernel(uint4* __restrict__ fz) {
  long gid = (long)blockIdx.x * 256 + threadIdx.x;
  if (gid < 49152L) { uint4 z; z.x = z.y = z.z = z.w = 0u; fz[gid] = z; }
}

#define MFMA __builtin_amdgcn_mfma_f32_16x16x32_bf16

// ---- persistent GRU: L0 = R13 champion protocol; L1 = detached (tagged, no ack) ----
template<int L>
__device__ __forceinline__ void gru_wave(int lb, int tid,
    const float* __restrict__ x,
    const float* __restrict__ whh, const float* __restrict__ wih,
    const float* __restrict__ bih, const float* __restrict__ bhh,
    u64* __restrict__ y0buf, u64* __restrict__ h1ring,
    u64* __restrict__ f0,
    float* __restrict__ dout,
    short* __restrict__ wlds, float (*part)[4][4][16][17])
{
  constexpr int KW  = L ? 2048 : 1280;  // K = [h(1024) | x(1024 or 256)]
  constexpr int WS  = KW + 8;           // padded LDS row stride (shorts)
  constexpr int NC  = L ? 8 : 16;       // cols per block
  constexpr int NR  = 3 * NC;
  constexpr int KXs = L ? 1024 : 256;   // wih inner stride
  const int cb = lb * NC;
  const int w  = tid >> 6;
  const int l  = tid & 63;
  const int lr = l & 15, lq = l >> 4;
  const int c  = L ? (lr & 7) : lr;

  // ---- one-time: stage weights fp32 -> bf16 LDS ----
  for (int i = tid; i < NR * (KW / 8); i += 256) {
    int row = i / (KW / 8);
    int k   = (i % (KW / 8)) * 8;
    int g = row / NC, cc = row % NC;
    const float* src = (k < 1024) ? (whh + (long)(g * 1024 + cb + cc) * 1024 + k)
                                  : (wih + (long)(g * 1024 + cb + cc) * KXs + (k - 1024));
    float4 a = *(const float4*)src;
    float4 b = *(const float4*)(src + 4);
    uint4 t4;
    t4.x = pkbf(a.x, a.y); t4.y = pkbf(a.z, a.w);
    t4.z = pkbf(b.x, b.y); t4.w = pkbf(b.z, b.w);
    *(uint4*)(wlds + row * WS + k) = t4;
  }

  const int gb = tid >> (L ? 3 : 4);
  const int gc = tid & (NC - 1);
  const bool isg = tid < 16 * NC;
  float bir = 0, biz = 0, bin = 0, bhr = 0, bhz = 0, bhn = 0;
  if (isg) {
    bir = bih[cb + gc];        bhr = bhh[cb + gc];
    biz = bih[1024 + cb + gc]; bhz = bhh[1024 + cb + gc];
    bin = bih[2048 + cb + gc]; bhn = bhh[2048 + cb + gc];
  }
  __syncthreads();

  const short* w0 = wlds + (0 * NC + c) * WS;
  const short* w1 = wlds + (1 * NC + c) * WS;
  const short* w2 = wlds + (2 * NC + c) * WS;

  float hp = 0.f;

  for (int t = 0; t < T_; ++t) {
    floatx4 ar = {0.f, 0.f, 0.f, 0.f};
    floatx4 az = ar, anh = ar, anx = ar;

    if constexpr (L == 0) {
      // ---- x-part first (always ready) ----
#pragma unroll
      for (int j = 0; j < 2; ++j) {
        const int kt = w * 2 + j;
        const float* xs = x + (long)lr * 262144 + (long)t * 256 + kt * 32 + lq * 8;
        float4 a = *(const float4*)xs;
        float4 b = *(const float4*)(xs + 4);
        U16 u;
        u.d[0] = pkbf(a.x, a.y); u.d[1] = pkbf(a.z, a.w);
        u.d[2] = pkbf(b.x, b.y); u.d[3] = pkbf(b.z, b.w);
        const int ko = 1024 + kt * 32 + lq * 8;
        ar  = MFMA(u.v, *(const shortx8*)(w0 + ko), ar,  0, 0, 0);
        az  = MFMA(u.v, *(const shortx8*)(w1 + ko), az,  0, 0, 0);
        anx = MFMA(u.v, *(const shortx8*)(w2 + ko), anx, 0, 0, 0);
      }
      if (t > 0) {
        // ---- dense flag poll: 1 coalesced load/lane, 8 lines ----
        const u64* fp = f0 + (long)(t - 1) * 64 + l;
        for (;;) {
          u64 fl = lda(fp);
          if (__all(fl != 0)) break;
          __builtin_amdgcn_s_sleep(1);
        }
        // ---- bulk read exactly once (flag+ack guarantee validity) ----
        const u64* base = y0buf + ((long)(t - 1) * 16 + lr) * 256 + w * 64 + lq * 2;
        u64 q[16];
#pragma unroll
        for (int j = 0; j < 8; ++j) {
          q[2 * j]     = lda(base + j * 8);
          q[2 * j + 1] = lda(base + j * 8 + 1);
        }
#pragma unroll
        for (int j = 0; j < 8; ++j) {
          U16 u; u.q[0] = q[2 * j]; u.q[1] = q[2 * j + 1];
          const int ko = (w * 8 + j) * 32 + lq * 8;
          ar  = MFMA(u.v, *(const shortx8*)(w0 + ko), ar,  0, 0, 0);
          az  = MFMA(u.v, *(const shortx8*)(w1 + ko), az,  0, 0, 0);
          anh = MFMA(u.v, *(const shortx8*)(w2 + ko), anh, 0, 0, 0);
        }
      }
    } else {
      // ---- poll f0[t] (flag-gated y0 read), h1 tagged reads issued alongside ----
      {
        const u64* fy = f0 + (long)t * 64 + l;
        for (;;) {
          u64 fl = lda(fy);
          if (__all(fl != 0)) break;
          __builtin_amdgcn_s_sleep(1);
        }
      }
      const u64* yb = y0buf + ((long)t * 16 + lr) * 256 + w * 64 + lq * 2;
      const u64* hb = h1ring + ((long)((t - 1) & 3) * 16 + lr) * 512 + w * 128 + lq * 4;
      u64 qy[16], qh[32];
#pragma unroll
      for (int j = 0; j < 8; ++j) {
        qy[2 * j]     = lda(yb + j * 8);
        qy[2 * j + 1] = lda(yb + j * 8 + 1);
      }
      if (t > 0) {
#pragma unroll
        for (int j = 0; j < 8; ++j)
#pragma unroll
          for (int i2 = 0; i2 < 4; ++i2)
            qh[4 * j + i2] = lda(hb + j * 16 + i2);
      }
      // ---- y0-part MFMAs (qh reads fly underneath) ----
#pragma unroll
      for (int j = 0; j < 8; ++j) {
        U16 u; u.q[0] = qy[2 * j]; u.q[1] = qy[2 * j + 1];
        const int ko = 1024 + (w * 8 + j) * 32 + lq * 8;
        ar  = MFMA(u.v, *(const shortx8*)(w0 + ko), ar,  0, 0, 0);
        az  = MFMA(u.v, *(const shortx8*)(w1 + ko), az,  0, 0, 0);
        anx = MFMA(u.v, *(const shortx8*)(w2 + ko), anx, 0, 0, 0);
      }
      if (t > 0) {
        // ---- validate tags (1-period-stale => expected first-pass hit) ----
        const unsigned tg = (unsigned)t;
        for (;;) {
          bool ok = true;
#pragma unroll
          for (int j = 0; j < 32; ++j) ok &= ((unsigned)(qh[j] >> 32) == tg);
          if (__all(ok)) break;
          __builtin_amdgcn_s_sleep(2);
#pragma unroll
          for (int j = 0; j < 8; ++j)
#pragma unroll
            for (int i2 = 0; i2 < 4; ++i2)
              qh[4 * j + i2] = lda(hb + j * 16 + i2);
        }
#pragma unroll
        for (int j = 0; j < 8; ++j) {
          U16 u;
#pragma unroll
          for (int i2 = 0; i2 < 4; ++i2) u.d[i2] = (unsigned)qh[4 * j + i2];
          const int ko = (w * 8 + j) * 32 + lq * 8;
          ar  = MFMA(u.v, *(const shortx8*)(w0 + ko), ar,  0, 0, 0);
          az  = MFMA(u.v, *(const shortx8*)(w1 + ko), az,  0, 0, 0);
          anh = MFMA(u.v, *(const shortx8*)(w2 + ko), anh, 0, 0, 0);
        }
      }
    }

    // ---- cross-wave combine (double-buffered partials, one barrier) ----
    const int par = t & 1;
    if (L == 0 || lr < 8) {
#pragma unroll
      for (int r4 = 0; r4 < 4; ++r4) {
        const int b = lq * 4 + r4;          // row = batch (m89 C/D layout)
        part[par][w][0][b][lr] = ar[r4];
        part[par][w][1][b][lr] = az[r4];
        part[par][w][2][b][lr] = anh[r4];
        part[par][w][3][b][lr] = anx[r4];
      }
    }
    __syncthreads();

    float hn = 0.f;
    if (isg) {
      float sr = 0, sz = 0, snh = 0, snx = 0;
#pragma unroll
      for (int ww = 0; ww < 4; ++ww) {
        sr  += part[par][ww][0][gb][gc];
        sz  += part[par][ww][1][gb][gc];
        snh += part[par][ww][2][gb][gc];
        snx += part[par][ww][3][gb][gc];
      }
      float r = 1.f / (1.f + __expf(-(sr + bir + bhr)));
      float z = 1.f / (1.f + __expf(-(sz + biz + bhz)));
      float targ = snx + bin + r * (snh + bhn);
      float e2 = __expf(2.f * targ);
      float n = 1.f - 2.f / (e2 + 1.f);       // tanh
      hn = (1.f - z) * n + z * hp;
      hp = hn;
    }

    if constexpr (L == 0) {
      // ---- champion publish: stores -> vmcnt ack -> barrier -> single flag ----
      if (isg) {
        unsigned hv = f2bf(hn);
        unsigned v1 = (unsigned)__shfl_down((int)hv, 1);
        unsigned v2 = (unsigned)__shfl_down((int)hv, 2);
        unsigned v3 = (unsigned)__shfl_down((int)hv, 3);
        if ((gc & 3) == 0) {
          u64 word = (u64)(hv | (v1 << 16)) | ((u64)(v2 | (v3 << 16)) << 32);
          sta(y0buf + ((long)t * 16 + gb) * 256 + ((cb + gc) >> 2), word);
        }
      }
      asm volatile("s_waitcnt vmcnt(0)" ::: "memory");
      __syncthreads();
      if (tid == 0)
        sta(f0 + (long)t * 64 + lb, 1ull);
      if (isg && t == T_ - 1)
        dout[16777216L + (long)gb * 1024 + cb + gc] = hn;
    } else {
      // ---- detached publish: tagged words, fire-and-forget, no ack/flag ----
      if (isg) {
        unsigned hv = f2bf(hn);
        unsigned v1 = (unsigned)__shfl_down((int)hv, 1);
        if ((gc & 1) == 0) {
          u64 word = ((u64)(unsigned)(t + 1) << 32) | (hv | (v1 << 16));
          sta(h1ring + ((long)(t & 3) * 16 + gb) * 512 + ((cb + gc) >> 1), word);
        }
        unsigned fv = __float_as_uint(hn);
        unsigned f2v = (unsigned)__shfl_down((int)fv, 1);
        if ((gc & 1) == 0)
          *(u64*)(dout + (long)gb * 1048576 + (long)t * 1024 + cb + gc) =
              (u64)fv | ((u64)f2v << 32);
        if (t == T_ - 1)
          dout[16777216L + 16384 + (long)gb * 1024 + cb + gc] = hn;
      }
      // no second barrier: double-buffered partials make it redundant
    }
  }
}

__global__ __launch_bounds__(256, 1) void gru_kernel(
    const float* __restrict__ x,
    const float* __restrict__ whh0, const float* __restrict__ wih0,
    const float* __restrict__ bih0, const float* __restrict__ bhh0,
    const float* __restrict__ whh1, const float* __restrict__ wih1,
    const float* __restrict__ bih1, const float* __restrict__ bhh1,
    u64* y0buf, u64* h1ring, u64* f0, float* dout)
{
  __shared__ __align__(16) short wlds[48 * 1288];       // 123,648 B (L1 uses 24*2056)
  __shared__ float part[2][4][4][16][17];               //  34,816 B
  const int bid = blockIdx.x, tid = threadIdx.x;
  if (bid < 64)
    gru_wave<0>(bid, tid, x, whh0, wih0, bih0, bhh0, y0buf, h1ring, f0, dout, wlds, part);
  else
    gru_wave<1>(bid - 64, tid, x, whh1, wih1, bih1, bhh1, y0buf, h1ring, f0, dout, wlds, part);
}

extern "C" void kernel_launch(void* const* d_in, const int* in_sizes, int n_in,
                              void* d_out, int out_size, void* d_ws, size_t ws_size,
                              hipStream_t stream) {
  (void)in_sizes; (void)n_in; (void)out_size; (void)ws_size;
  const float* x    = (const float*)d_in[0];
  const float* wih0 = (const float*)d_in[2];
  const float* whh0 = (const float*)d_in[3];
  const float* bih0 = (const float*)d_in[4];
  const float* bhh0 = (const float*)d_in[5];
  const float* wih1 = (const float*)d_in[6];
  const float* whh1 = (const float*)d_in[7];
  const float* bih1 = (const float*)d_in[8];
  const float* bhh1 = (const float*)d_in[9];
  char* ws = (char*)d_ws;
  u64* y0buf  = (u64*)(ws + 0L);          // 33,554,432 B (write-once, flag-gated)
  u64* f0     = (u64*)(ws + 33554432L);   //    524,288 B dense flags (zeroed per launch)
  u64* h1ring = (u64*)(ws + 34078720L);   //    262,144 B tagged ring (4 slots, zeroed)
  float* out  = (float*)d_out;

  prep_kernel<<<192, 256, 0, stream>>>((uint4*)f0);   // zeroes f0 then h1ring (contiguous)
  gru_kernel<<<192, 256, 0, stream>>>(x, whh0, wih0, bih0, bhh0,
                                      whh1, wih1, bih1, bhh1,
                                      y0buf, h1ring, f0, out);
}

// Round 19
// 5760.342 us; speedup vs baseline: 1.9092x; 1.9092x over previous
//
#include <hip/hip_runtime.h>
#include <stdint.h>

#define T_ 1024

typedef float  floatx4 __attribute__((ext_vector_type(4)));
typedef short  shortx8 __attribute__((ext_vector_type(8)));
typedef unsigned long long u64;

union U16 { u64 q[2]; unsigned d[4]; shortx8 v; };

__device__ __forceinline__ unsigned short f2bf(float f) {
  union { float f; unsigned u; } v; v.f = f;
  return (unsigned short)((v.u + 0x7FFFu + ((v.u >> 16) & 1u)) >> 16);
}
__device__ __forceinline__ unsigned pkbf(float lo, float hi) {
  unsigned r;
  asm("v_cvt_pk_bf16_f32 %0, %1, %2" : "=v"(r) : "v"(lo), "v"(hi));
  return r;
}
__device__ __forceinline__ u64 lda(const u64* p) {
  return __hip_atomic_load(p, __ATOMIC_RELAXED, __HIP_MEMORY_SCOPE_AGENT);
}
__device__ __forceinline__ void sta(u64* p, u64 v) {
  __hip_atomic_store(p, v, __ATOMIC_RELAXED, __HIP_MEMORY_SCOPE_AGENT);
}

// ---- prep: zero dense flags (1.5 MB) ----
__global__ void prep_kernel(uint4* __restrict__ fz) {
  long gid = (long)blockIdx.x * 256 + threadIdx.x;
  if (gid < 98304L) { uint4 z; z.x = z.y = z.z = z.w = 0u; fz[gid] = z; }
}

#define MFMA __builtin_amdgcn_mfma_f32_16x16x32_bf16

// ---- persistent GRU: dense per-block flags, thin detect, read-once (R13 champion) ----
template<int L>
__device__ __forceinline__ void gru_wave(int lb, int tid,
    const float* __restrict__ x,
    const float* __restrict__ whh, const float* __restrict__ wih,
    const float* __restrict__ bih, const float* __restrict__ bhh,
    u64* __restrict__ y0buf, u64* __restrict__ h1ring,
    u64* __restrict__ f0, u64* __restrict__ f1,
    float* __restrict__ dout,
    short* __restrict__ wlds, float (*part)[4][4][16][18])
{
  constexpr int KW  = L ? 2048 : 1280;  // K = [h(1024) | x(1024 or 256)]
  constexpr int WS  = KW + 8;           // padded LDS row stride (shorts)
  constexpr int NC  = L ? 8 : 16;       // cols per block
  constexpr int NR  = 3 * NC;
  constexpr int KXs = L ? 1024 : 256;   // wih inner stride
  const int cb = lb * NC;
  const int w  = tid >> 6;
  const int l  = tid & 63;
  const int lr = l & 15, lq = l >> 4;
  const int c  = L ? (lr & 7) : lr;

  // ---- one-time: stage weights fp32 -> bf16 LDS ----
  for (int i = tid; i < NR * (KW / 8); i += 256) {
    int row = i / (KW / 8);
    int k   = (i % (KW / 8)) * 8;
    int g = row / NC, cc = row % NC;
    const float* src = (k < 1024) ? (whh + (long)(g * 1024 + cb + cc) * 1024 + k)
                                  : (wih + (long)(g * 1024 + cb + cc) * KXs + (k - 1024));
    float4 a = *(const float4*)src;
    float4 b = *(const float4*)(src + 4);
    uint4 t4;
    t4.x = pkbf(a.x, a.y); t4.y = pkbf(a.z, a.w);
    t4.z = pkbf(b.x, b.y); t4.w = pkbf(b.z, b.w);
    *(uint4*)(wlds + row * WS + k) = t4;
  }

  const int gb = tid >> (L ? 3 : 4);
  const int gc = tid & (NC - 1);
  const bool isg = tid < 16 * NC;
  float bir = 0, biz = 0, bin = 0, bhr = 0, bhz = 0, bhn = 0;
  if (isg) {
    bir = bih[cb + gc];        bhr = bhh[cb + gc];
    biz = bih[1024 + cb + gc]; bhz = bhh[1024 + cb + gc];
    bin = bih[2048 + cb + gc]; bhn = bhh[2048 + cb + gc];
  }
  __syncthreads();

  const short* w0 = wlds + (0 * NC + c) * WS;
  const short* w1 = wlds + (1 * NC + c) * WS;
  const short* w2 = wlds + (2 * NC + c) * WS;

  float hp = 0.f;

  for (int t = 0; t < T_; ++t) {
    floatx4 ar = {0.f, 0.f, 0.f, 0.f};
    floatx4 az = ar, anh = ar, anx = ar;

    if constexpr (L == 0) {
      // ---- x-part first (always ready) ----
#pragma unroll
      for (int j = 0; j < 2; ++j) {
        const int kt = w * 2 + j;
        const float* xs = x + (long)lr * 262144 + (long)t * 256 + kt * 32 + lq * 8;
        float4 a = *(const float4*)xs;
        float4 b = *(const float4*)(xs + 4);
        U16 u;
        u.d[0] = pkbf(a.x, a.y); u.d[1] = pkbf(a.z, a.w);
        u.d[2] = pkbf(b.x, b.y); u.d[3] = pkbf(b.z, b.w);
        const int ko = 1024 + kt * 32 + lq * 8;
        ar  = MFMA(u.v, *(const shortx8*)(w0 + ko), ar,  0, 0, 0);
        az  = MFMA(u.v, *(const shortx8*)(w1 + ko), az,  0, 0, 0);
        anx = MFMA(u.v, *(const shortx8*)(w2 + ko), anx, 0, 0, 0);
      }
      if (t > 0) {
        // ---- dense flag poll: 1 coalesced load/lane, 8 lines/wave ----
        const u64* fp = f0 + (long)(t - 1) * 64 + l;
        for (;;) {
          u64 fl = lda(fp);
          if (__all(fl != 0)) break;
          __builtin_amdgcn_s_sleep(1);
        }
        // ---- bulk read exactly once ----
        const u64* base = y0buf + ((long)(t - 1) * 16 + lr) * 256 + w * 64 + lq * 2;
        u64 q[16];
#pragma unroll
        for (int j = 0; j < 8; ++j) {
          q[2 * j]     = lda(base + j * 8);
          q[2 * j + 1] = lda(base + j * 8 + 1);
        }
#pragma unroll
        for (int j = 0; j < 8; ++j) {
          U16 u; u.q[0] = q[2 * j]; u.q[1] = q[2 * j + 1];
          const int ko = (w * 8 + j) * 32 + lq * 8;
          ar  = MFMA(u.v, *(const shortx8*)(w0 + ko), ar,  0, 0, 0);
          az  = MFMA(u.v, *(const shortx8*)(w1 + ko), az,  0, 0, 0);
          anh = MFMA(u.v, *(const shortx8*)(w2 + ko), anh, 0, 0, 0);
        }
      }
    } else {
      // ---- split-wait: f0[t] -> issue y0 reads -> f1[t-1] (y0 in flight) ----
      {
        const u64* fy = f0 + (long)t * 64 + l;
        for (;;) {
          u64 fl = lda(fy);
          if (__all(fl != 0)) break;
          __builtin_amdgcn_s_sleep(1);
        }
      }
      const u64* yb = y0buf + ((long)t * 16 + lr) * 256 + w * 64 + lq * 2;
      u64 qy[16], qh[16];
#pragma unroll
      for (int j = 0; j < 8; ++j) {
        qy[2 * j]     = lda(yb + j * 8);
        qy[2 * j + 1] = lda(yb + j * 8 + 1);
      }
      if (t > 0) {
        const u64* fh = f1 + (long)(t - 1) * 128 + l;
        for (;;) {
          u64 a = lda(fh), b = lda(fh + 64);
          if (__all(a != 0 && b != 0)) break;
          __builtin_amdgcn_s_sleep(1);
        }
        const u64* hb = h1ring + ((long)((t - 1) & 7) * 16 + lr) * 256 + w * 64 + lq * 2;
#pragma unroll
        for (int j = 0; j < 8; ++j) {
          qh[2 * j]     = lda(hb + j * 8);
          qh[2 * j + 1] = lda(hb + j * 8 + 1);
        }
      }
#pragma unroll
      for (int j = 0; j < 8; ++j) {
        U16 u; u.q[0] = qy[2 * j]; u.q[1] = qy[2 * j + 1];
        const int ko = 1024 + (w * 8 + j) * 32 + lq * 8;
        ar  = MFMA(u.v, *(const shortx8*)(w0 + ko), ar,  0, 0, 0);
        az  = MFMA(u.v, *(const shortx8*)(w1 + ko), az,  0, 0, 0);
        anx = MFMA(u.v, *(const shortx8*)(w2 + ko), anx, 0, 0, 0);
      }
      if (t > 0) {
#pragma unroll
        for (int j = 0; j < 8; ++j) {
          U16 u; u.q[0] = qh[2 * j]; u.q[1] = qh[2 * j + 1];
          const int ko = (w * 8 + j) * 32 + lq * 8;
          ar  = MFMA(u.v, *(const shortx8*)(w0 + ko), ar,  0, 0, 0);
          az  = MFMA(u.v, *(const shortx8*)(w1 + ko), az,  0, 0, 0);
          anh = MFMA(u.v, *(const shortx8*)(w2 + ko), anh, 0, 0, 0);
        }
      }
    }

    // ---- cross-wave combine (double-buffered partials, stride 18 = 2-way banks) ----
    const int par = t & 1;
    if (L == 0 || lr < 8) {
#pragma unroll
      for (int r4 = 0; r4 < 4; ++r4) {
        const int b = lq * 4 + r4;          // row = batch (m89 C/D layout)
        part[par][w][0][b][lr] = ar[r4];
        part[par][w][1][b][lr] = az[r4];
        part[par][w][2][b][lr] = anh[r4];
        part[par][w][3][b][lr] = anx[r4];
      }
    }
    __syncthreads();

    float hn = 0.f;
    if (isg) {
      float sr = 0, sz = 0, snh = 0, snx = 0;
#pragma unroll
      for (int ww = 0; ww < 4; ++ww) {
        sr  += part[par][ww][0][gb][gc];
        sz  += part[par][ww][1][gb][gc];
        snh += part[par][ww][2][gb][gc];
        snx += part[par][ww][3][gb][gc];
      }
      float r = 1.f / (1.f + __expf(-(sr + bir + bhr)));
      float z = 1.f / (1.f + __expf(-(sz + biz + bhz)));
      float targ = snx + bin + r * (snh + bhn);
      float e2 = __expf(2.f * targ);
      float n = 1.f - 2.f / (e2 + 1.f);       // tanh
      hn = (1.f - z) * n + z * hp;
      hp = hn;

      // ---- exchange stores (fire into the fabric) ----
      unsigned hv = f2bf(hn);
      unsigned v1 = (unsigned)__shfl_down((int)hv, 1);
      unsigned v2 = (unsigned)__shfl_down((int)hv, 2);
      unsigned v3 = (unsigned)__shfl_down((int)hv, 3);
      if ((gc & 3) == 0) {
        u64 word = (u64)(hv | (v1 << 16)) | ((u64)(v2 | (v3 << 16)) << 32);
        if constexpr (L == 0)
          sta(y0buf + ((long)t * 16 + gb) * 256 + ((cb + gc) >> 2), word);
        else
          sta(h1ring + ((long)(t & 7) * 16 + gb) * 256 + ((cb + gc) >> 2), word);
      }
    }

    // ---- block-level publish: vmcnt(0) all waves -> barrier -> 1 flag ----
    asm volatile("s_waitcnt vmcnt(0)" ::: "memory");
    __syncthreads();
    if (tid == 0)
      sta((L ? f1 + (long)t * 128 : f0 + (long)t * 64) + lb, 1ull);

    // ---- pure outputs (off critical path) ----
    if (isg) {
      if constexpr (L == 1) {
        unsigned fv = __float_as_uint(hn);
        unsigned f2v = (unsigned)__shfl_down((int)fv, 1);
        if ((gc & 1) == 0)
          *(u64*)(dout + (long)gb * 1048576 + (long)t * 1024 + cb + gc) =
              (u64)fv | ((u64)f2v << 32);
        if (t == T_ - 1)
          dout[16777216L + 16384 + (long)gb * 1024 + cb + gc] = hn;
      } else {
        if (t == T_ - 1)
          dout[16777216L + (long)gb * 1024 + cb + gc] = hn;
      }
    }
  }
}

__global__ __launch_bounds__(256, 1) void gru_kernel(
    const float* __restrict__ x,
    const float* __restrict__ whh0, const float* __restrict__ wih0,
    const float* __restrict__ bih0, const float* __restrict__ bhh0,
    const float* __restrict__ whh1, const float* __restrict__ wih1,
    const float* __restrict__ bih1, const float* __restrict__ bhh1,
    u64* y0buf, u64* h1ring, u64* f0, u64* f1, float* dout)
{
  __shared__ __align__(16) short wlds[48 * 1288];       // 123,648 B (L1 uses 24*2056)
  __shared__ float part[2][4][4][16][18];               //  36,864 B (stride-18: 2-way banks)
  const int bid = blockIdx.x, tid = threadIdx.x;
  if (bid < 64)
    gru_wave<0>(bid, tid, x, whh0, wih0, bih0, bhh0, y0buf, h1ring, f0, f1, dout, wlds, part);
  else
    gru_wave<1>(bid - 64, tid, x, whh1, wih1, bih1, bhh1, y0buf, h1ring, f0, f1, dout, wlds, part);
}

extern "C" void kernel_launch(void* const* d_in, const int* in_sizes, int n_in,
                              void* d_out, int out_size, void* d_ws, size_t ws_size,
                              hipStream_t stream) {
  (void)in_sizes; (void)n_in; (void)out_size; (void)ws_size;
  const float* x    = (const float*)d_in[0];
  const float* wih0 = (const float*)d_in[2];
  const float* whh0 = (const float*)d_in[3];
  const float* bih0 = (const float*)d_in[4];
  const float* bhh0 = (const float*)d_in[5];
  const float* wih1 = (const float*)d_in[6];
  const float* whh1 = (const float*)d_in[7];
  const float* bih1 = (const float*)d_in[8];
  const float* bhh1 = (const float*)d_in[9];
  char* ws = (char*)d_ws;
  u64* y0buf  = (u64*)(ws + 0L);          // 33,554,432 B (write-once per launch)
  u64* h1ring = (u64*)(ws + 33554432L);   //    262,144 B (8 slots, drift<=1)
  u64* f0     = (u64*)(ws + 33816576L);   //    524,288 B dense flags (zeroed per launch)
  u64* f1     = (u64*)(ws + 34340864L);   //  1,048,576 B dense flags (zeroed per launch)
  float* out  = (float*)d_out;

  prep_kernel<<<384, 256, 0, stream>>>((uint4*)f0);   // zeroes f0 then f1 (contiguous)
  gru_kernel<<<192, 256, 0, stream>>>(x, whh0, wih0, bih0, bhh0,
                                      whh1, wih1, bih1, bhh1,
                                      y0buf, h1ring, f0, f1, out);
}